// Round 1
// baseline (149.760 us; speedup 1.0000x reference)
//
#include <hip/hip_runtime.h>

typedef __bf16 bf16x8 __attribute__((ext_vector_type(8)));
typedef float  f32x4  __attribute__((ext_vector_type(4)));

#define IC    256
#define OC    256
#define Hh    64
#define Ww    64
#define Bb    16
#define DLEN  512
#define KKTOT 2304        // IC*9
#define HP    66          // padded spatial
#define MODSCALE 0.0625f                 // sqrt(2/512)
#define WSCALE   0.029462782549439484f   // sqrt(2/2304)

// workspace layout (bytes)
#define XT_ELEMS  (Bb*HP*HP*IC)          // 17,842,176 bf16
#define XT_BYTES  (XT_ELEMS*2)           // 35,684,352
#define WMAT_OFF  XT_BYTES
#define WMAT_BYTES (OC*KKTOT*2)          // 1,179,648
#define S_OFF     (WMAT_OFF + WMAT_BYTES)

typedef const __attribute__((address_space(1))) unsigned int* gptr_t;
typedef __attribute__((address_space(3))) unsigned int* lptr_t;

__device__ __forceinline__ void gl2lds16(const void* g, void* l) {
  __builtin_amdgcn_global_load_lds((gptr_t)g, (lptr_t)l, 16, 0, 0);
}

// ---------------- s[b][ic] = sum_dl style[b][dl]*mod_weight[ic][dl]*MODSCALE
__global__ void k_style(const float* __restrict__ style,
                        const float* __restrict__ mw,
                        float* __restrict__ s_out) {
  __shared__ float st[DLEN];
  const int b = blockIdx.x, t = threadIdx.x;
  st[t]       = style[b*DLEN + t];
  st[t + 256] = style[b*DLEN + t + 256];
  __syncthreads();
  const float4* mwr = (const float4*)(mw + (long)t*DLEN);
  float acc = 0.f;
  #pragma unroll 4
  for (int d = 0; d < DLEN/4; ++d) {
    float4 v = mwr[d];
    acc += v.x*st[d*4] + v.y*st[d*4+1] + v.z*st[d*4+2] + v.w*st[d*4+3];
  }
  s_out[b*IC + t] = acc * MODSCALE;
}

// ---------------- wmat[oc][(kh*3+kw)*256+ic] = bf16(w * WSCALE * demod[oc])
__global__ void k_wmat(const float* __restrict__ wt, __bf16* __restrict__ wmat) {
  const int oc = blockIdx.x, t = threadIdx.x;   // t = ic
  float w9[9];
  const float* p = wt + ((long)oc*IC + t)*9;
  float ss = 0.f;
  #pragma unroll
  for (int r = 0; r < 9; ++r) { w9[r] = p[r]; ss += w9[r]*w9[r]; }
  #pragma unroll
  for (int off = 32; off; off >>= 1) ss += __shfl_down(ss, off, 64);
  __shared__ float red[4];
  if ((t & 63) == 0) red[t >> 6] = ss;
  __syncthreads();
  float total = red[0] + red[1] + red[2] + red[3];
  float dm = WSCALE / sqrtf(total + 1e-8f);
  #pragma unroll
  for (int r = 0; r < 9; ++r)
    wmat[oc*KKTOT + r*IC + t] = (__bf16)(w9[r] * dm);
}

// ---------------- zero xt
__global__ void k_zero(uint4* __restrict__ p, int n16) {
  const uint4 z = {0u,0u,0u,0u};
  for (int i = blockIdx.x*256 + threadIdx.x; i < n16; i += gridDim.x*256) p[i] = z;
}

// ---------------- xt[b][y+1][x+1][ic] = bf16(image[b][ic][y][x] * s[b][ic]) (NHWC, padded)
__global__ void k_xmod(const float* __restrict__ img,
                       const float* __restrict__ s,
                       __bf16* __restrict__ xt) {
  __shared__ float tile[64][69];
  const int t   = threadIdx.x;
  const int b   = blockIdx.x >> 8;
  const int rem = blockIdx.x & 255;
  const int y   = rem >> 2;          // source row 0..63
  const int ic0 = (rem & 3) << 6;    // ic block of 64
  #pragma unroll
  for (int r = 0; r < 4; ++r) {
    int seg = r*256 + t;
    int i   = seg >> 4;              // ic offset 0..63
    int x0  = (seg & 15) * 4;
    float4 v = *(const float4*)(img + (((long)(b*IC + ic0 + i)*Hh + y)*Ww + x0));
    float sv = s[b*IC + ic0 + i];
    tile[i][x0+0] = v.x*sv; tile[i][x0+1] = v.y*sv;
    tile[i][x0+2] = v.z*sv; tile[i][x0+3] = v.w*sv;
  }
  __syncthreads();
  const int x  = t >> 2;
  const int j0 = (t & 3) << 4;
  bf16x8 o0, o1;
  #pragma unroll
  for (int e = 0; e < 8; ++e) o0[e] = (__bf16)tile[j0 + e][x];
  #pragma unroll
  for (int e = 0; e < 8; ++e) o1[e] = (__bf16)tile[j0 + 8 + e][x];
  __bf16* dst = xt + (((long)(b*HP + y + 1)*HP + (x + 1))*IC + ic0 + j0);
  ((bf16x8*)dst)[0] = o0;
  ((bf16x8*)dst)[1] = o1;
}

// ---------------- implicit-GEMM conv: out[b][oc][hw] over K=2304
__global__ __launch_bounds__(256) void k_conv(const __bf16* __restrict__ wmat,
                                              const __bf16* __restrict__ xt,
                                              float* __restrict__ out) {
  __shared__ __align__(128) __bf16 As[128*64];   // [ocRow][k] swizzled
  __shared__ __align__(128) __bf16 Bs[128*64];   // [hwRow][k(ic)] swizzled
  const int tid  = threadIdx.x;
  const int lane = tid & 63;
  const int wv   = tid >> 6;
  const int blk  = blockIdx.x;
  const int b    = blk >> 6;
  const int rem  = blk & 63;
  const int ocBase = (rem & 1) << 7;
  const int hwBase = (rem >> 1) << 7;

  long aoff[4], boff[4];
  unsigned ldsoff[4];
  #pragma unroll
  for (int j = 0; j < 4; ++j) {
    int seg = (j*4 + wv)*64 + lane;
    int row = seg >> 3;
    int c   = (seg & 7) ^ (row & 7);            // pre-swizzled global source
    aoff[j] = (long)(ocBase + row)*KKTOT + c*8;
    int hw = hwBase + row;
    int y = hw >> 6, x = hw & 63;
    boff[j] = ((long)(b*HP + y)*HP + x)*IC + c*8;
    ldsoff[j] = (unsigned)((j*4 + wv) << 10);   // 1 KiB per wave-call
  }

  f32x4 acc[4][4] = {};

  const int wr  = wv >> 1, wc = wv & 1;
  const int rA0 = wr*64 + (lane & 15);
  const int rB0 = wc*64 + (lane & 15);
  const int cb  = (lane >> 4) * 16;             // byte col within 128B row

  char* AsB = (char*)As;
  char* BsB = (char*)Bs;

  for (int ks = 0; ks < 36; ++ks) {
    const int pos = ks >> 2;
    const int kh  = pos / 3, kw = pos - kh*3;
    const long bstep = (long)((kh*HP + kw)*IC + ((ks & 3) << 6));
    const long astep = (long)(ks << 6);
    #pragma unroll
    for (int j = 0; j < 4; ++j) {
      gl2lds16(wmat + aoff[j] + astep, AsB + ldsoff[j]);
      gl2lds16(xt   + boff[j] + bstep, BsB + ldsoff[j]);
    }
    __syncthreads();
    #pragma unroll
    for (int ksub = 0; ksub < 2; ++ksub) {
      bf16x8 af[4], bfr[4];
      #pragma unroll
      for (int m = 0; m < 4; ++m) {
        int r = rA0 + m*16;
        int cByte = (ksub*64 + cb) ^ ((r & 7) << 4);
        af[m] = *(const bf16x8*)(AsB + r*128 + cByte);
      }
      #pragma unroll
      for (int n = 0; n < 4; ++n) {
        int r = rB0 + n*16;
        int cByte = (ksub*64 + cb) ^ ((r & 7) << 4);
        bfr[n] = *(const bf16x8*)(BsB + r*128 + cByte);
      }
      #pragma unroll
      for (int m = 0; m < 4; ++m)
        #pragma unroll
        for (int n = 0; n < 4; ++n)
          acc[m][n] = __builtin_amdgcn_mfma_f32_16x16x32_bf16(af[m], bfr[n], acc[m][n], 0, 0, 0);
    }
    __syncthreads();
  }

  float* outb = out + (long)b * (OC*Hh*Ww);
  const int oc0 = ocBase + wr*64 + (lane >> 4)*4;
  const int hw0 = hwBase + wc*64 + (lane & 15);
  #pragma unroll
  for (int m = 0; m < 4; ++m)
    #pragma unroll
    for (int n = 0; n < 4; ++n)
      #pragma unroll
      for (int j = 0; j < 4; ++j)
        outb[(long)(oc0 + m*16 + j)*(Hh*Ww) + hw0 + n*16] = acc[m][n][j];
}

extern "C" void kernel_launch(void* const* d_in, const int* in_sizes, int n_in,
                              void* d_out, int out_size, void* d_ws, size_t ws_size,
                              hipStream_t stream) {
  const float* image = (const float*)d_in[0];
  const float* style = (const float*)d_in[1];
  const float* weight= (const float*)d_in[2];
  const float* modw  = (const float*)d_in[3];
  float* out = (float*)d_out;

  char* ws = (char*)d_ws;
  __bf16* xt   = (__bf16*)ws;
  __bf16* wmat = (__bf16*)(ws + WMAT_OFF);
  float*  sbuf = (float*)(ws + S_OFF);

  k_style<<<Bb, 256, 0, stream>>>(style, modw, sbuf);
  k_wmat<<<OC, 256, 0, stream>>>(weight, wmat);
  k_zero<<<2048, 256, 0, stream>>>((uint4*)xt, XT_BYTES/16);
  k_xmod<<<Bb*64*4, 256, 0, stream>>>(image, sbuf, xt);
  k_conv<<<Bb*64, 256, 0, stream>>>(wmat, xt, out);
}

// Round 3
// 114.195 us; speedup vs baseline: 1.3114x; 1.3114x over previous
//
#include <hip/hip_runtime.h>

typedef __bf16 bf16x8 __attribute__((ext_vector_type(8)));
typedef float  f32x4  __attribute__((ext_vector_type(4)));

#define IC    256
#define OC    256
#define Hh    64
#define Ww    64
#define Bb    16
#define DLEN  512
#define KKTOT 2304        // IC*9
#define HP    66          // padded spatial
#define MODSCALE 0.0625f                 // sqrt(2/512)
#define WSCALE   0.029462782549439484f   // sqrt(2/2304)

// workspace layout (bytes)
#define XT_ELEMS  (Bb*HP*HP*IC)          // 17,842,176 bf16
#define XT_BYTES  (XT_ELEMS*2)           // 35,684,352
#define WMAT_OFF  XT_BYTES
#define WMAT_BYTES (OC*KKTOT*2)          // 1,179,648
#define S_OFF     (WMAT_OFF + WMAT_BYTES)

typedef const __attribute__((address_space(1))) unsigned int* gptr_t;
typedef __attribute__((address_space(3))) unsigned int* lptr_t;

__device__ __forceinline__ void gl2lds16(const void* g, void* l) {
  __builtin_amdgcn_global_load_lds((gptr_t)g, (lptr_t)l, 16, 0, 0);
}

#define BARRIER()    __builtin_amdgcn_s_barrier()
#define WAIT_LGKM0() asm volatile("s_waitcnt lgkmcnt(0)" ::: "memory")
#define WAIT_VM4()   asm volatile("s_waitcnt vmcnt(4)" ::: "memory")
#define WAIT_VM0()   asm volatile("s_waitcnt vmcnt(0)" ::: "memory")

// ---------------- s[b][ic] = sum_dl style[b][dl]*mod_weight[ic][dl]*MODSCALE
__global__ void k_style(const float* __restrict__ style,
                        const float* __restrict__ mw,
                        float* __restrict__ s_out) {
  __shared__ float st[DLEN];
  const int b = blockIdx.x, t = threadIdx.x;
  st[t]       = style[b*DLEN + t];
  st[t + 256] = style[b*DLEN + t + 256];
  __syncthreads();
  const float4* mwr = (const float4*)(mw + (long)t*DLEN);
  float acc = 0.f;
  #pragma unroll 4
  for (int d = 0; d < DLEN/4; ++d) {
    float4 v = mwr[d];
    acc += v.x*st[d*4] + v.y*st[d*4+1] + v.z*st[d*4+2] + v.w*st[d*4+3];
  }
  s_out[b*IC + t] = acc * MODSCALE;
}

// ---------------- wmat[oc][(kh*3+kw)*256+ic] = bf16(w * WSCALE * demod[oc])
__global__ void k_wmat(const float* __restrict__ wt, __bf16* __restrict__ wmat) {
  const int oc = blockIdx.x, t = threadIdx.x;   // t = ic
  float w9[9];
  const float* p = wt + ((long)oc*IC + t)*9;
  float ss = 0.f;
  #pragma unroll
  for (int r = 0; r < 9; ++r) { w9[r] = p[r]; ss += w9[r]*w9[r]; }
  #pragma unroll
  for (int off = 32; off; off >>= 1) ss += __shfl_down(ss, off, 64);
  __shared__ float red[4];
  if ((t & 63) == 0) red[t >> 6] = ss;
  __syncthreads();
  float total = red[0] + red[1] + red[2] + red[3];
  float dm = WSCALE / sqrtf(total + 1e-8f);
  #pragma unroll
  for (int r = 0; r < 9; ++r)
    wmat[oc*KKTOT + r*IC + t] = (__bf16)(w9[r] * dm);
}

// ---------------- zero only the halo of xt (interior overwritten by k_xmod)
__global__ void k_halo(__bf16* __restrict__ xt) {
  const int b = blockIdx.x, t = threadIdx.x;
  uint4* base = (uint4*)(xt + (long)b*HP*HP*IC);
  const uint4 z = {0u,0u,0u,0u};
  // rows y=0 and y=65 (each 66*256 elems = 2112 uint4)
  for (int i = t; i < 2112; i += 256) { base[i] = z; base[137280 + i] = z; }
  // cols x=0 and x=65 for y=1..64 (each 256 elems = 32 uint4 per y)
  for (int i = t; i < 64*32; i += 256) {
    int y = 1 + (i >> 5), c = i & 31;
    base[y*2112 + c] = z;
    base[y*2112 + 2080 + c] = z;
  }
}

// ---------------- xt[b][y+1][x+1][ic] = bf16(image[b][ic][y][x] * s[b][ic]) (NHWC, padded)
__global__ void k_xmod(const float* __restrict__ img,
                       const float* __restrict__ s,
                       __bf16* __restrict__ xt) {
  __shared__ float tile[64][69];
  const int t   = threadIdx.x;
  const int b   = blockIdx.x >> 8;
  const int rem = blockIdx.x & 255;
  const int y   = rem >> 2;          // source row 0..63
  const int ic0 = (rem & 3) << 6;    // ic block of 64
  #pragma unroll
  for (int r = 0; r < 4; ++r) {
    int seg = r*256 + t;
    int i   = seg >> 4;              // ic offset 0..63
    int x0  = (seg & 15) * 4;
    float4 v = *(const float4*)(img + (((long)(b*IC + ic0 + i)*Hh + y)*Ww + x0));
    float sv = s[b*IC + ic0 + i];
    tile[i][x0+0] = v.x*sv; tile[i][x0+1] = v.y*sv;
    tile[i][x0+2] = v.z*sv; tile[i][x0+3] = v.w*sv;
  }
  __syncthreads();
  const int x  = t >> 2;
  const int j0 = (t & 3) << 4;
  bf16x8 o0, o1;
  #pragma unroll
  for (int e = 0; e < 8; ++e) o0[e] = (__bf16)tile[j0 + e][x];
  #pragma unroll
  for (int e = 0; e < 8; ++e) o1[e] = (__bf16)tile[j0 + 8 + e][x];
  __bf16* dst = xt + (((long)(b*HP + y + 1)*HP + (x + 1))*IC + ic0 + j0);
  ((bf16x8*)dst)[0] = o0;
  ((bf16x8*)dst)[1] = o1;
}

// ---------------- 256x256x64 8-phase implicit-GEMM conv
// C[oc, hw] = sum_k wmat[oc][k] * xt[(b, y+kh, x+kw)][ic],  K = 2304 = 36 tiles of 64
__global__ __launch_bounds__(512, 2) void k_conv(const __bf16* __restrict__ wmat,
                                                 const __bf16* __restrict__ xt,
                                                 float* __restrict__ out) {
  __shared__ __attribute__((aligned(128))) char ldsc[131072]; // 2 bufs x (A 32K | B 32K)
  const int tid  = threadIdx.x;
  const int lane = tid & 63;
  const int wv   = tid >> 6;
  const int wr   = wv >> 2;            // 0..1  (M group, 128 rows)
  const int wc   = wv & 3;             // 0..3  (N group, 64 cols)

  // bijective XCD remap: i = (b>>1) + 8*tile + 128*(b&1)
  const int bi     = blockIdx.x;
  const int b      = ((bi & 7) << 1) | ((bi >> 7) & 1);
  const int hwBase = ((bi >> 3) & 15) << 8;

  // ---- staging precompute (2 x 16B loads per thread per half-tile)
  const int row0 = tid >> 3;                    // 0..63 (row within half, l=0)
  const int c8   = (tid & 7) ^ (row0 & 7);      // pre-swizzled 16B-chunk col
  const long aOff0 = (long)row0*KKTOT + c8*8;
  const long aOff1 = aOff0 + (long)64*KKTOT;    // l=1 row = row0+64, same c8
  const int x  = row0;                          // hw & 63
  const int y0 = hwBase >> 6;
  long bOff[2][2];
  #pragma unroll
  for (int h = 0; h < 2; ++h)
    #pragma unroll
    for (int l = 0; l < 2; ++l)
      bOff[h][l] = (((long)b*HP + y0 + 2*h + l)*HP + x)*IC + c8*8;
  const unsigned wvOff = wv << 10;

#define STAGE_A(tt, h) do {                                              \
    char* d_ = ldsc + (((tt)&1)<<16) + ((h)<<14) + wvOff;                \
    const __bf16* g_ = wmat + (h)*(128*KKTOT) + (tt)*64;                 \
    gl2lds16(g_ + aOff0, d_);                                            \
    gl2lds16(g_ + aOff1, d_ + 8192);                                     \
  } while (0)

#define STAGE_B(tt, h, sb) do {                                          \
    char* d_ = ldsc + (((tt)&1)<<16) + 32768 + ((h)<<14) + wvOff;        \
    gl2lds16(xt + bOff[h][0] + (sb), d_);                                \
    gl2lds16(xt + bOff[h][1] + (sb), d_ + 8192);                         \
  } while (0)

  // ---- prologue: A(0)h0,h1  B(0)h0,h1  B(1)h0,h1 ; wait oldest 4 half-tiles
  STAGE_A(0, 0); STAGE_A(0, 1);
  STAGE_B(0, 0, 0);  STAGE_B(0, 1, 0);    // tile 0: kh=kw=0, ksub 0
  STAGE_B(1, 0, 64); STAGE_B(1, 1, 64);   // tile 1: kh=kw=0, ksub 1
  WAIT_VM4();
  BARRIER();

  f32x4 acc[8][4] = {};
  const int cb = (lane >> 4) << 4;        // 16B col within 128B row
  const int rA = wr*128 + (lane & 15);
  const int rB = wc*64  + (lane & 15);

  for (int t = 0; t < 36; ++t) {
    char* Abuf = ldsc + ((t & 1) << 16);
    char* Bbuf = Abuf + 32768;
    int sbB = 0;
    if (t < 34) {
      int tt = t + 2, pos = tt >> 2, kh = pos/3;
      sbB = (kh*HP + (pos - kh*3))*IC + ((tt & 3) << 6);
    }
    bf16x8 bfr[4][2];

    #pragma unroll
    for (int q = 0; q < 4; ++q) {
      if (q == 0) {
        #pragma unroll
        for (int n = 0; n < 4; ++n) {
          int rr = rB + n*16, sw = (rr & 7) << 4;
          bfr[n][0] = *(const bf16x8*)(Bbuf + rr*128 + ((  0 + cb) ^ sw));
          bfr[n][1] = *(const bf16x8*)(Bbuf + rr*128 + (( 64 + cb) ^ sw));
        }
      }
      bf16x8 af[2][2];
      #pragma unroll
      for (int m2 = 0; m2 < 2; ++m2) {
        int rr = rA + q*32 + m2*16, sw = (rr & 7) << 4;
        af[m2][0] = *(const bf16x8*)(Abuf + rr*128 + ((  0 + cb) ^ sw));
        af[m2][1] = *(const bf16x8*)(Abuf + rr*128 + (( 64 + cb) ^ sw));
      }
      // one half-tile prefetch per phase
      if      (q == 0) { if (t < 35) STAGE_A(t+1, 0); }
      else if (q == 1) { if (t < 35) STAGE_A(t+1, 1); }
      else if (q == 2) { if (t < 34) STAGE_B(t+2, 0, sbB); }
      else             { if (t < 34) STAGE_B(t+2, 1, sbB); }
      BARRIER();
      WAIT_LGKM0();
      __builtin_amdgcn_s_setprio(1);
      #pragma unroll
      for (int m2 = 0; m2 < 2; ++m2)
        #pragma unroll
        for (int n = 0; n < 4; ++n) {
          acc[q*2+m2][n] = __builtin_amdgcn_mfma_f32_16x16x32_bf16(af[m2][0], bfr[n][0], acc[q*2+m2][n], 0, 0, 0);
          acc[q*2+m2][n] = __builtin_amdgcn_mfma_f32_16x16x32_bf16(af[m2][1], bfr[n][1], acc[q*2+m2][n], 0, 0, 0);
        }
      __builtin_amdgcn_s_setprio(0);
      if (q == 3) { if (t >= 34) { WAIT_VM0(); } else { WAIT_VM4(); } }
      BARRIER();
    }
  }

  // ---- epilogue: scalar f32 stores (16-lane = 64B cacheline segments)
  float* outb = out + (((long)b*OC + wr*128 + ((lane >> 4) << 2))*(Hh*Ww))
                    + hwBase + wc*64 + (lane & 15);
  #pragma unroll
  for (int m = 0; m < 8; ++m)
    #pragma unroll
    for (int n = 0; n < 4; ++n)
      #pragma unroll
      for (int j = 0; j < 4; ++j)
        outb[((long)(m*16 + j))*(Hh*Ww) + n*16] = acc[m][n][j];
}

extern "C" void kernel_launch(void* const* d_in, const int* in_sizes, int n_in,
                              void* d_out, int out_size, void* d_ws, size_t ws_size,
                              hipStream_t stream) {
  const float* image = (const float*)d_in[0];
  const float* style = (const float*)d_in[1];
  const float* weight= (const float*)d_in[2];
  const float* modw  = (const float*)d_in[3];
  float* out = (float*)d_out;

  char* ws = (char*)d_ws;
  __bf16* xt   = (__bf16*)ws;
  __bf16* wmat = (__bf16*)(ws + WMAT_OFF);
  float*  sbuf = (float*)(ws + S_OFF);

  k_style<<<Bb, 256, 0, stream>>>(style, modw, sbuf);
  k_wmat<<<OC, 256, 0, stream>>>(weight, wmat);
  k_halo<<<Bb, 256, 0, stream>>>(xt);
  k_xmod<<<Bb*64*4, 256, 0, stream>>>(image, sbuf, xt);
  k_conv<<<256, 512, 0, stream>>>(wmat, xt, out);
}

// Round 4
// 113.453 us; speedup vs baseline: 1.3200x; 1.0065x over previous
//
#include <hip/hip_runtime.h>

typedef __bf16 bf16x8 __attribute__((ext_vector_type(8)));
typedef float  f32x4  __attribute__((ext_vector_type(4)));

#define IC    256
#define OC    256
#define Hh    64
#define Ww    64
#define Bb    16
#define DLEN  512
#define KKTOT 2304        // IC*9
#define HP    66          // padded spatial
#define MODSCALE 0.0625f                 // sqrt(2/512)
#define WSCALE   0.029462782549439484f   // sqrt(2/2304)

// workspace layout (bytes)
#define XT_ELEMS  (Bb*HP*HP*IC)          // 17,842,176 bf16
#define XT_BYTES  (XT_ELEMS*2)           // 35,684,352
#define WMAT_OFF  XT_BYTES
#define WMAT_BYTES (OC*KKTOT*2)          // 1,179,648
#define S_OFF     (WMAT_OFF + WMAT_BYTES)

typedef const __attribute__((address_space(1))) unsigned int* gptr_t;
typedef __attribute__((address_space(3))) unsigned int* lptr_t;

__device__ __forceinline__ void gl2lds16(const void* g, void* l) {
  __builtin_amdgcn_global_load_lds((gptr_t)g, (lptr_t)l, 16, 0, 0);
}

#define BARRIER()    __builtin_amdgcn_s_barrier()
#define WAIT_VM4()   asm volatile("s_waitcnt vmcnt(4)" ::: "memory")
#define WAIT_VM0()   asm volatile("s_waitcnt vmcnt(0)" ::: "memory")

// ---------------- s[b][ic] = sum_dl style[b][dl]*mod_weight[ic][dl]*MODSCALE
__global__ void k_style(const float* __restrict__ style,
                        const float* __restrict__ mw,
                        float* __restrict__ s_out) {
  __shared__ float st[DLEN];
  const int b = blockIdx.x, t = threadIdx.x;
  st[t]       = style[b*DLEN + t];
  st[t + 256] = style[b*DLEN + t + 256];
  __syncthreads();
  const float4* mwr = (const float4*)(mw + (long)t*DLEN);
  float acc = 0.f;
  #pragma unroll 4
  for (int d = 0; d < DLEN/4; ++d) {
    float4 v = mwr[d];
    acc += v.x*st[d*4] + v.y*st[d*4+1] + v.z*st[d*4+2] + v.w*st[d*4+3];
  }
  s_out[b*IC + t] = acc * MODSCALE;
}

// ---------------- wmat[oc][(kh*3+kw)*256+ic] = bf16(w * WSCALE * demod[oc])
__global__ void k_wmat(const float* __restrict__ wt, __bf16* __restrict__ wmat) {
  const int oc = blockIdx.x, t = threadIdx.x;   // t = ic
  float w9[9];
  const float* p = wt + ((long)oc*IC + t)*9;
  float ss = 0.f;
  #pragma unroll
  for (int r = 0; r < 9; ++r) { w9[r] = p[r]; ss += w9[r]*w9[r]; }
  #pragma unroll
  for (int off = 32; off; off >>= 1) ss += __shfl_down(ss, off, 64);
  __shared__ float red[4];
  if ((t & 63) == 0) red[t >> 6] = ss;
  __syncthreads();
  float total = red[0] + red[1] + red[2] + red[3];
  float dm = WSCALE / sqrtf(total + 1e-8f);
  #pragma unroll
  for (int r = 0; r < 9; ++r)
    wmat[oc*KKTOT + r*IC + t] = (__bf16)(w9[r] * dm);
}

// ---------------- zero only the halo of xt (interior overwritten by k_xmod)
__global__ void k_halo(__bf16* __restrict__ xt) {
  const int b = blockIdx.x, t = threadIdx.x;
  uint4* base = (uint4*)(xt + (long)b*HP*HP*IC);
  const uint4 z = {0u,0u,0u,0u};
  for (int i = t; i < 2112; i += 256) { base[i] = z; base[137280 + i] = z; }
  for (int i = t; i < 64*32; i += 256) {
    int y = 1 + (i >> 5), c = i & 31;
    base[y*2112 + c] = z;
    base[y*2112 + 2080 + c] = z;
  }
}

// ---------------- xt[b][y+1][x+1][ic] = bf16(image[b][ic][y][x] * s[b][ic]) (NHWC, padded)
__global__ void k_xmod(const float* __restrict__ img,
                       const float* __restrict__ s,
                       __bf16* __restrict__ xt) {
  __shared__ float tile[64][69];
  const int t   = threadIdx.x;
  const int b   = blockIdx.x >> 8;
  const int rem = blockIdx.x & 255;
  const int y   = rem >> 2;          // source row 0..63
  const int ic0 = (rem & 3) << 6;    // ic block of 64
  #pragma unroll
  for (int r = 0; r < 4; ++r) {
    int seg = r*256 + t;
    int i   = seg >> 4;              // ic offset 0..63
    int x0  = (seg & 15) * 4;
    float4 v = *(const float4*)(img + (((long)(b*IC + ic0 + i)*Hh + y)*Ww + x0));
    float sv = s[b*IC + ic0 + i];
    tile[i][x0+0] = v.x*sv; tile[i][x0+1] = v.y*sv;
    tile[i][x0+2] = v.z*sv; tile[i][x0+3] = v.w*sv;
  }
  __syncthreads();
  const int x  = t >> 2;
  const int j0 = (t & 3) << 4;
  bf16x8 o0, o1;
  #pragma unroll
  for (int e = 0; e < 8; ++e) o0[e] = (__bf16)tile[j0 + e][x];
  #pragma unroll
  for (int e = 0; e < 8; ++e) o1[e] = (__bf16)tile[j0 + 8 + e][x];
  __bf16* dst = xt + (((long)(b*HP + y + 1)*HP + (x + 1))*IC + ic0 + j0);
  ((bf16x8*)dst)[0] = o0;
  ((bf16x8*)dst)[1] = o1;
}

// ---------------- 256x256x64 8-phase implicit-GEMM conv, A-frag register pipeline
// C[oc, hw] = sum_k wmat[oc][k] * xt[(b, y+kh, x+kw)][ic],  K = 2304 = 36 tiles of 64
__global__ __launch_bounds__(512, 2) void k_conv(const __bf16* __restrict__ wmat,
                                                 const __bf16* __restrict__ xt,
                                                 float* __restrict__ out) {
  __shared__ __attribute__((aligned(128))) char ldsc[131072]; // 2 bufs x (A 32K | B 32K)
  const int tid  = threadIdx.x;
  const int lane = tid & 63;
  const int wv   = tid >> 6;
  const int wr   = wv >> 2;            // 0..1  (M group, 128 rows)
  const int wc   = wv & 3;             // 0..3  (N group, 64 cols)

  // bijective XCD remap
  const int bi     = blockIdx.x;
  const int b      = ((bi & 7) << 1) | ((bi >> 7) & 1);
  const int hwBase = ((bi >> 3) & 15) << 8;

  // ---- staging precompute (2 x 16B loads per thread per half-tile)
  const int row0 = tid >> 3;                    // 0..63 (row within half, l=0)
  const int c8   = (tid & 7) ^ (row0 & 7);      // pre-swizzled 16B-chunk col
  const long aOff0 = (long)row0*KKTOT + c8*8;
  const long aOff1 = aOff0 + (long)64*KKTOT;
  const int x  = row0;
  const int y0 = hwBase >> 6;
  long bOff[2][2];
  #pragma unroll
  for (int h = 0; h < 2; ++h)
    #pragma unroll
    for (int l = 0; l < 2; ++l)
      bOff[h][l] = (((long)b*HP + y0 + 2*h + l)*HP + x)*IC + c8*8;
  const unsigned wvOff = wv << 10;

#define STAGE_A(tt, h) do {                                              \
    char* d_ = ldsc + (((tt)&1)<<16) + ((h)<<14) + wvOff;                \
    const __bf16* g_ = wmat + (h)*(128*KKTOT) + (tt)*64;                 \
    gl2lds16(g_ + aOff0, d_);                                            \
    gl2lds16(g_ + aOff1, d_ + 8192);                                     \
  } while (0)

#define STAGE_B(tt, h, sb) do {                                          \
    char* d_ = ldsc + (((tt)&1)<<16) + 32768 + ((h)<<14) + wvOff;        \
    gl2lds16(xt + bOff[h][0] + (sb), d_);                                \
    gl2lds16(xt + bOff[h][1] + (sb), d_ + 8192);                         \
  } while (0)

  // ---- prologue
  STAGE_A(0, 0); STAGE_A(0, 1);
  STAGE_B(0, 0, 0);  STAGE_B(0, 1, 0);
  STAGE_B(1, 0, 64); STAGE_B(1, 1, 64);
  WAIT_VM4();
  BARRIER();

  f32x4 acc[8][4] = {};
  bf16x8 af[2][2][2];   // [set][m2][ksub] ping-pong: set = q&1
  bf16x8 bfr[4][2];
  const int cb = (lane >> 4) << 4;
  const int rA = wr*128 + (lane & 15);
  const int rB = wc*64  + (lane & 15);

#define READ_A(set, q) do {                                              \
    _Pragma("unroll")                                                    \
    for (int m2 = 0; m2 < 2; ++m2) {                                     \
      int rr = rA + (q)*32 + m2*16, sw = (rr & 7) << 4;                  \
      af[set][m2][0] = *(const bf16x8*)(Abuf + rr*128 + ((  0 + cb) ^ sw)); \
      af[set][m2][1] = *(const bf16x8*)(Abuf + rr*128 + (( 64 + cb) ^ sw)); \
    }                                                                    \
  } while (0)

#define MFMA_Q(set, q) do {                                              \
    __builtin_amdgcn_s_setprio(1);                                       \
    _Pragma("unroll")                                                    \
    for (int m2 = 0; m2 < 2; ++m2)                                       \
      _Pragma("unroll")                                                  \
      for (int n = 0; n < 4; ++n) {                                      \
        acc[(q)*2+m2][n] = __builtin_amdgcn_mfma_f32_16x16x32_bf16(af[set][m2][0], bfr[n][0], acc[(q)*2+m2][n], 0, 0, 0); \
        acc[(q)*2+m2][n] = __builtin_amdgcn_mfma_f32_16x16x32_bf16(af[set][m2][1], bfr[n][1], acc[(q)*2+m2][n], 0, 0, 0); \
      }                                                                  \
    __builtin_amdgcn_s_setprio(0);                                       \
  } while (0)

  for (int t = 0; t < 36; ++t) {
    char* Abuf = ldsc + ((t & 1) << 16);
    char* Bbuf = Abuf + 32768;
    int sbB = 0;
    if (t < 34) {
      int tt = t + 2, pos = tt >> 2, kh = pos/3;
      sbB = (kh*HP + (pos - kh*3))*IC + ((tt & 3) << 6);
    }

    // ---- q0: read own A[q0] + B(all) (waited) + A[q1] (pipelined)
    READ_A(0, 0);
    #pragma unroll
    for (int n = 0; n < 4; ++n) {
      int rr = rB + n*16, sw = (rr & 7) << 4;
      bfr[n][0] = *(const bf16x8*)(Bbuf + rr*128 + ((  0 + cb) ^ sw));
      bfr[n][1] = *(const bf16x8*)(Bbuf + rr*128 + (( 64 + cb) ^ sw));
    }
    READ_A(1, 1);
    if (t < 35) STAGE_A(t+1, 0);
    BARRIER();
    MFMA_Q(0, 0);
    BARRIER();

    // ---- q1: read A[q2] (pipelined)
    READ_A(0, 2);
    if (t < 35) STAGE_A(t+1, 1);
    BARRIER();
    MFMA_Q(1, 1);
    BARRIER();

    // ---- q2: read A[q3] (pipelined)
    READ_A(1, 3);
    if (t < 34) STAGE_B(t+2, 0, sbB);
    BARRIER();
    MFMA_Q(0, 2);
    BARRIER();

    // ---- q3: no reads
    if (t < 34) STAGE_B(t+2, 1, sbB);
    BARRIER();
    MFMA_Q(1, 3);
    if (t >= 34) { WAIT_VM0(); } else { WAIT_VM4(); }
    BARRIER();
  }

  // ---- epilogue
  float* outb = out + (((long)b*OC + wr*128 + ((lane >> 4) << 2))*(Hh*Ww))
                    + hwBase + wc*64 + (lane & 15);
  #pragma unroll
  for (int m = 0; m < 8; ++m)
    #pragma unroll
    for (int n = 0; n < 4; ++n)
      #pragma unroll
      for (int j = 0; j < 4; ++j)
        outb[((long)(m*16 + j))*(Hh*Ww) + n*16] = acc[m][n][j];
}

extern "C" void kernel_launch(void* const* d_in, const int* in_sizes, int n_in,
                              void* d_out, int out_size, void* d_ws, size_t ws_size,
                              hipStream_t stream) {
  const float* image = (const float*)d_in[0];
  const float* style = (const float*)d_in[1];
  const float* weight= (const float*)d_in[2];
  const float* modw  = (const float*)d_in[3];
  float* out = (float*)d_out;

  char* ws = (char*)d_ws;
  __bf16* xt   = (__bf16*)ws;
  __bf16* wmat = (__bf16*)(ws + WMAT_OFF);
  float*  sbuf = (float*)(ws + S_OFF);

  k_style<<<Bb, 256, 0, stream>>>(style, modw, sbuf);
  k_wmat<<<OC, 256, 0, stream>>>(weight, wmat);
  k_halo<<<Bb, 256, 0, stream>>>(xt);
  k_xmod<<<Bb*64*4, 256, 0, stream>>>(image, sbuf, xt);
  k_conv<<<256, 512, 0, stream>>>(wmat, xt, out);
}

// Round 5
// 108.689 us; speedup vs baseline: 1.3779x; 1.0438x over previous
//
#include <hip/hip_runtime.h>

typedef __bf16 bf16x8 __attribute__((ext_vector_type(8)));
typedef float  f32x4  __attribute__((ext_vector_type(4)));

#define IC    256
#define OC    256
#define Hh    64
#define Ww    64
#define Bb    16
#define DLEN  512
#define KKTOT 2304        // IC*9
#define HP    66          // padded spatial
#define MODSCALE 0.0625f                 // sqrt(2/512)
#define WSCALE   0.029462782549439484f   // sqrt(2/2304)

// workspace layout (bytes)
#define XT_ELEMS  (Bb*HP*HP*IC)          // 17,842,176 bf16
#define XT_BYTES  (XT_ELEMS*2)           // 35,684,352
#define WMAT_OFF  XT_BYTES
#define WMAT_BYTES (OC*KKTOT*2)          // 1,179,648
#define S_OFF     (WMAT_OFF + WMAT_BYTES)

typedef const __attribute__((address_space(1))) unsigned int* gptr_t;
typedef __attribute__((address_space(3))) unsigned int* lptr_t;

__device__ __forceinline__ void gl2lds16(const void* g, void* l) {
  __builtin_amdgcn_global_load_lds((gptr_t)g, (lptr_t)l, 16, 0, 0);
}

// ---------------- s[b][ic] = sum_dl style[b][dl]*mod_weight[ic][dl]*MODSCALE
__global__ void k_style(const float* __restrict__ style,
                        const float* __restrict__ mw,
                        float* __restrict__ s_out) {
  __shared__ float st[DLEN];
  const int b = blockIdx.x, t = threadIdx.x;
  st[t]       = style[b*DLEN + t];
  st[t + 256] = style[b*DLEN + t + 256];
  __syncthreads();
  const float4* mwr = (const float4*)(mw + (long)t*DLEN);
  float acc = 0.f;
  #pragma unroll 4
  for (int d = 0; d < DLEN/4; ++d) {
    float4 v = mwr[d];
    acc += v.x*st[d*4] + v.y*st[d*4+1] + v.z*st[d*4+2] + v.w*st[d*4+3];
  }
  s_out[b*IC + t] = acc * MODSCALE;
}

// ---------------- wmat[oc][(kh*3+kw)*256+ic] = bf16(w * WSCALE * demod[oc])
__global__ void k_wmat(const float* __restrict__ wt, __bf16* __restrict__ wmat) {
  const int oc = blockIdx.x, t = threadIdx.x;   // t = ic
  float w9[9];
  const float* p = wt + ((long)oc*IC + t)*9;
  float ss = 0.f;
  #pragma unroll
  for (int r = 0; r < 9; ++r) { w9[r] = p[r]; ss += w9[r]*w9[r]; }
  #pragma unroll
  for (int off = 32; off; off >>= 1) ss += __shfl_down(ss, off, 64);
  __shared__ float red[4];
  if ((t & 63) == 0) red[t >> 6] = ss;
  __syncthreads();
  float total = red[0] + red[1] + red[2] + red[3];
  float dm = WSCALE / sqrtf(total + 1e-8f);
  #pragma unroll
  for (int r = 0; r < 9; ++r)
    wmat[oc*KKTOT + r*IC + t] = (__bf16)(w9[r] * dm);
}

// ---------------- zero only the halo of xt (interior overwritten by k_xmod)
__global__ void k_halo(__bf16* __restrict__ xt) {
  const int b = blockIdx.x, t = threadIdx.x;
  uint4* base = (uint4*)(xt + (long)b*HP*HP*IC);
  const uint4 z = {0u,0u,0u,0u};
  for (int i = t; i < 2112; i += 256) { base[i] = z; base[137280 + i] = z; }
  for (int i = t; i < 64*32; i += 256) {
    int y = 1 + (i >> 5), c = i & 31;
    base[y*2112 + c] = z;
    base[y*2112 + 2080 + c] = z;
  }
}

// ---------------- xt[b][y+1][x+1][ic] = bf16(image[b][ic][y][x] * s[b][ic]) (NHWC, padded)
__global__ void k_xmod(const float* __restrict__ img,
                       const float* __restrict__ s,
                       __bf16* __restrict__ xt) {
  __shared__ float tile[64][69];
  const int t   = threadIdx.x;
  const int b   = blockIdx.x >> 8;
  const int rem = blockIdx.x & 255;
  const int y   = rem >> 2;          // source row 0..63
  const int ic0 = (rem & 3) << 6;    // ic block of 64
  #pragma unroll
  for (int r = 0; r < 4; ++r) {
    int seg = r*256 + t;
    int i   = seg >> 4;              // ic offset 0..63
    int x0  = (seg & 15) * 4;
    float4 v = *(const float4*)(img + (((long)(b*IC + ic0 + i)*Hh + y)*Ww + x0));
    float sv = s[b*IC + ic0 + i];
    tile[i][x0+0] = v.x*sv; tile[i][x0+1] = v.y*sv;
    tile[i][x0+2] = v.z*sv; tile[i][x0+3] = v.w*sv;
  }
  __syncthreads();
  const int x  = t >> 2;
  const int j0 = (t & 3) << 4;
  bf16x8 o0, o1;
  #pragma unroll
  for (int e = 0; e < 8; ++e) o0[e] = (__bf16)tile[j0 + e][x];
  #pragma unroll
  for (int e = 0; e < 8; ++e) o1[e] = (__bf16)tile[j0 + 8 + e][x];
  __bf16* dst = xt + (((long)(b*HP + y + 1)*HP + (x + 1))*IC + ic0 + j0);
  ((bf16x8*)dst)[0] = o0;
  ((bf16x8*)dst)[1] = o1;
}

// ---------------- 256x256x64 implicit-GEMM conv, ONE barrier per K-tile
// C[oc, hw] = sum_k wmat[oc][k] * xt[(b, y+kh, x+kw)][ic],  K = 2304 = 36 tiles of 64
// Sync design: dbuf parity p = t&1. Tile t stages A(t+1),B(t+1) into parity ~p,
// whose readers (tile t-1) all passed the tile-(t-1) __syncthreads(). Loads are
// issued in phases q0/q1 (>=1500cyc before the tile-end vmcnt(0)) so the drain
// is ~free. __syncthreads() (not raw s_barrier) so ds_reads can't sink past it.
__global__ __launch_bounds__(512, 2) void k_conv(const __bf16* __restrict__ wmat,
                                                 const __bf16* __restrict__ xt,
                                                 float* __restrict__ out) {
  __shared__ __attribute__((aligned(128))) char ldsc[131072]; // 2 bufs x (A 32K | B 32K)
  const int tid  = threadIdx.x;
  const int lane = tid & 63;
  const int wv   = tid >> 6;
  const int wr   = wv >> 2;            // 0..1  (M group, 128 rows)
  const int wc   = wv & 3;             // 0..3  (N group, 64 cols)

  // bijective XCD remap
  const int bi     = blockIdx.x;
  const int b      = ((bi & 7) << 1) | ((bi >> 7) & 1);
  const int hwBase = ((bi >> 3) & 15) << 8;

  // ---- staging precompute (2 x 16B loads per thread per half-tile)
  const int row0 = tid >> 3;                    // 0..63 (row within half, l=0)
  const int c8   = (tid & 7) ^ (row0 & 7);      // pre-swizzled 16B-chunk col
  const long aOff0 = (long)row0*KKTOT + c8*8;
  const long aOff1 = aOff0 + (long)64*KKTOT;
  const int x  = row0;
  const int y0 = hwBase >> 6;
  long bOff[2][2];
  #pragma unroll
  for (int h = 0; h < 2; ++h)
    #pragma unroll
    for (int l = 0; l < 2; ++l)
      bOff[h][l] = (((long)b*HP + y0 + 2*h + l)*HP + x)*IC + c8*8;
  const unsigned wvOff = wv << 10;

#define STAGE_A(tt, h) do {                                              \
    char* d_ = ldsc + (((tt)&1)<<16) + ((h)<<14) + wvOff;                \
    const __bf16* g_ = wmat + (h)*(128*KKTOT) + (tt)*64;                 \
    gl2lds16(g_ + aOff0, d_);                                            \
    gl2lds16(g_ + aOff1, d_ + 8192);                                     \
  } while (0)

#define STAGE_B(tt, h, sb) do {                                          \
    char* d_ = ldsc + (((tt)&1)<<16) + 32768 + ((h)<<14) + wvOff;        \
    gl2lds16(xt + bOff[h][0] + (sb), d_);                                \
    gl2lds16(xt + bOff[h][1] + (sb), d_ + 8192);                         \
  } while (0)

  // ---- prologue: tile 0 (parity 0), sb=0
  STAGE_A(0, 0); STAGE_A(0, 1);
  STAGE_B(0, 0, 0); STAGE_B(0, 1, 0);
  __syncthreads();

  f32x4 acc[8][4] = {};
  bf16x8 af[2][2];      // [m2][ksub] for current quadrant
  bf16x8 bfr[4][2];
  const int cb = (lane >> 4) << 4;
  const int rA = wr*128 + (lane & 15);
  const int rB = wc*64  + (lane & 15);

#define READ_A(q) do {                                                   \
    _Pragma("unroll")                                                    \
    for (int m2 = 0; m2 < 2; ++m2) {                                     \
      int rr = rA + (q)*32 + m2*16, sw = (rr & 7) << 4;                  \
      af[m2][0] = *(const bf16x8*)(Abuf + rr*128 + ((  0 + cb) ^ sw));   \
      af[m2][1] = *(const bf16x8*)(Abuf + rr*128 + (( 64 + cb) ^ sw));   \
    }                                                                    \
  } while (0)

// k-outer ordering: dependency distance 8 between same-acc MFMAs
#define MFMA_Q(q) do {                                                   \
    __builtin_amdgcn_s_setprio(1);                                       \
    _Pragma("unroll")                                                    \
    for (int ks = 0; ks < 2; ++ks)                                       \
      _Pragma("unroll")                                                  \
      for (int m2 = 0; m2 < 2; ++m2)                                     \
        _Pragma("unroll")                                                \
        for (int n = 0; n < 4; ++n)                                      \
          acc[(q)*2+m2][n] = __builtin_amdgcn_mfma_f32_16x16x32_bf16(af[m2][ks], bfr[n][ks], acc[(q)*2+m2][n], 0, 0, 0); \
    __builtin_amdgcn_s_setprio(0);                                       \
  } while (0)

  for (int t = 0; t < 36; ++t) {
    char* Abuf = ldsc + ((t & 1) << 16);
    char* Bbuf = Abuf + 32768;
    const int tt = t + 1, pos = tt >> 2, kh = pos/3;
    const int sb1 = (kh*HP + (pos - kh*3))*IC + ((tt & 3) << 6);

    // ---- q0: B frags + A[q0]; stage half 0 of next tile (A and B)
    #pragma unroll
    for (int n = 0; n < 4; ++n) {
      int rr = rB + n*16, sw = (rr & 7) << 4;
      bfr[n][0] = *(const bf16x8*)(Bbuf + rr*128 + ((  0 + cb) ^ sw));
      bfr[n][1] = *(const bf16x8*)(Bbuf + rr*128 + (( 64 + cb) ^ sw));
    }
    READ_A(0);
    if (t < 35) { STAGE_A(tt, 0); STAGE_B(tt, 0, sb1); }
    MFMA_Q(0);

    // ---- q1: A[q1]; stage half 1 of next tile
    READ_A(1);
    if (t < 35) { STAGE_A(tt, 1); STAGE_B(tt, 1, sb1); }
    MFMA_Q(1);

    // ---- q2, q3: pure compute + reads (free-running)
    READ_A(2);
    MFMA_Q(2);
    READ_A(3);
    MFMA_Q(3);

    // single sync point per tile: fence + barrier + implicit vmcnt/lgkm drain.
    // Loads were issued >= half a tile ago -> drain is cheap.
    __syncthreads();
  }

  // ---- epilogue
  float* outb = out + (((long)b*OC + wr*128 + ((lane >> 4) << 2))*(Hh*Ww))
                    + hwBase + wc*64 + (lane & 15);
  #pragma unroll
  for (int m = 0; m < 8; ++m)
    #pragma unroll
    for (int n = 0; n < 4; ++n)
      #pragma unroll
      for (int j = 0; j < 4; ++j)
        outb[((long)(m*16 + j))*(Hh*Ww) + n*16] = acc[m][n][j];
}

extern "C" void kernel_launch(void* const* d_in, const int* in_sizes, int n_in,
                              void* d_out, int out_size, void* d_ws, size_t ws_size,
                              hipStream_t stream) {
  const float* image = (const float*)d_in[0];
  const float* style = (const float*)d_in[1];
  const float* weight= (const float*)d_in[2];
  const float* modw  = (const float*)d_in[3];
  float* out = (float*)d_out;

  char* ws = (char*)d_ws;
  __bf16* xt   = (__bf16*)ws;
  __bf16* wmat = (__bf16*)(ws + WMAT_OFF);
  float*  sbuf = (float*)(ws + S_OFF);

  k_style<<<Bb, 256, 0, stream>>>(style, modw, sbuf);
  k_wmat<<<OC, 256, 0, stream>>>(weight, wmat);
  k_halo<<<Bb, 256, 0, stream>>>(xt);
  k_xmod<<<Bb*64*4, 256, 0, stream>>>(image, sbuf, xt);
  k_conv<<<256, 512, 0, stream>>>(wmat, xt, out);
}